// Round 7
// baseline (503.296 us; speedup 1.0000x reference)
//
#include <hip/hip_runtime.h>

#define DIM 128
#define NPB 32          // nodes per block in fused (4 waves x 8 nodes)
#define SCAN_CHUNK 1024 // nodes per scanA block
#define BK_BITS 6       // 64 nodes per bucket

typedef unsigned int   uint32;
typedef unsigned short uint16;

__device__ __forceinline__ uint16 f32_to_bf16_rne(float f) {
    uint32 u = __float_as_uint(f);
    u += 0x7fffu + ((u >> 16) & 1u);
    return (uint16)(u >> 16);
}

// ===========================================================================
// prep: [0,64) transpose W ; [64,64+nConv) h->bf16 ; rest: per-node histogram
// ===========================================================================
__global__ __launch_bounds__(256) void prep_kernel(
    const float* __restrict__ W, float* __restrict__ Wt,
    const float* __restrict__ h, uint16* __restrict__ hb,
    const int* __restrict__ dst, int* __restrict__ cnt,
    int E, long long ND, int nConv, int doConv)
{
    const int bid = blockIdx.x;
    const int tid = threadIdx.x;
    if (bid < 64) {
        const int i = bid * 256 + tid;
        const int j = i >> 7, d = i & 127;
        Wt[d * DIM + j] = W[i];
    } else if (doConv && bid < 64 + nConv) {
        const long long base = ((long long)(bid - 64) * 256 + tid) * 8;
        if (base + 8 <= ND) {
            const float4 a = *(const float4*)&h[base];
            const float4 c = *(const float4*)&h[base + 4];
            uint4 v;
            v.x = (uint32)f32_to_bf16_rne(a.x) | ((uint32)f32_to_bf16_rne(a.y) << 16);
            v.y = (uint32)f32_to_bf16_rne(a.z) | ((uint32)f32_to_bf16_rne(a.w) << 16);
            v.z = (uint32)f32_to_bf16_rne(c.x) | ((uint32)f32_to_bf16_rne(c.y) << 16);
            v.w = (uint32)f32_to_bf16_rne(c.z) | ((uint32)f32_to_bf16_rne(c.w) << 16);
            *(uint4*)&hb[base] = v;
        }
    } else {
        const int hbase = 64 + (doConv ? nConv : 0);
        const long long e = ((long long)(bid - hbase) * 256 + tid) * 4;
        if (e + 4 <= E) {
            const int4 d4 = *(const int4*)&dst[e];
            atomicAdd(&cnt[d4.x], 1);
            atomicAdd(&cnt[d4.y], 1);
            atomicAdd(&cnt[d4.z], 1);
            atomicAdd(&cnt[d4.w], 1);
        } else {
            for (long long k = e; k < E && k < e + 4; ++k) atomicAdd(&cnt[dst[k]], 1);
        }
    }
}

// ---- scanA: per-chunk local exclusive scan + chunk totals -----------------
__global__ __launch_bounds__(256) void scanA_kernel(const int* __restrict__ cnt,
                                                    int* __restrict__ pos,
                                                    int* __restrict__ bsum, int N)
{
    __shared__ int ts[256];
    const int t = threadIdx.x;
    const int base = blockIdx.x * SCAN_CHUNK + t * 4;
    int v[4];
    int s = 0;
#pragma unroll
    for (int k = 0; k < 4; ++k) {
        v[k] = (base + k < N) ? cnt[base + k] : 0;
        s += v[k];
    }
    ts[t] = s;
    __syncthreads();
    for (int off = 1; off < 256; off <<= 1) {
        int x = (t >= off) ? ts[t - off] : 0;
        __syncthreads();
        ts[t] += x;
        __syncthreads();
    }
    int run = (t == 0) ? 0 : ts[t - 1];
    if (t == 255) bsum[blockIdx.x] = ts[255];
#pragma unroll
    for (int k = 0; k < 4; ++k) {
        if (base + k < N) pos[base + k] = run;   // LOCAL exclusive start
        run += v[k];
    }
}

// ---- scanB: exclusive scan of chunk totals + init bucket append ptrs ------
__global__ __launch_bounds__(1024) void scanB_kernel(int* __restrict__ bsum, int nb,
                                                     const int* __restrict__ pos,
                                                     int* __restrict__ bptr, int nbuck)
{
    __shared__ int ts[1024];
    const int t = threadIdx.x;
    ts[t] = (t < nb) ? bsum[t] : 0;
    __syncthreads();
    for (int off = 1; off < 1024; off <<= 1) {
        int x = (t >= off) ? ts[t - off] : 0;
        __syncthreads();
        ts[t] += x;
        __syncthreads();
    }
    if (t < nb) bsum[t] = (t == 0) ? 0 : ts[t - 1];   // chunk global offsets
    // bucket b (64 nodes) global start = excl_chunk + pos[b<<6]
    for (int bk = t; bk < nbuck; bk += 1024) {
        const int chunk = bk >> 4;               // (bk<<6)>>10
        const int ec = (chunk == 0) ? 0 : ts[chunk - 1];
        bptr[bk] = ec + pos[bk << 6];
    }
}

// ---- scatter: radix-partition edges into dst-buckets ----------------------
__global__ __launch_bounds__(256) void scatter_kernel(
    const int* __restrict__ src, const int* __restrict__ dst,
    int* __restrict__ bptr, int2* __restrict__ ebuf, int E)
{
    const long long e = ((long long)blockIdx.x * 256 + threadIdx.x) * 4;
    if (e + 4 <= E) {
        const int4 s4 = *(const int4*)&src[e];
        const int4 d4 = *(const int4*)&dst[e];
        int sl;
        sl = atomicAdd(&bptr[d4.x >> BK_BITS], 1); ebuf[sl] = make_int2(s4.x, d4.x);
        sl = atomicAdd(&bptr[d4.y >> BK_BITS], 1); ebuf[sl] = make_int2(s4.y, d4.y);
        sl = atomicAdd(&bptr[d4.z >> BK_BITS], 1); ebuf[sl] = make_int2(s4.z, d4.z);
        sl = atomicAdd(&bptr[d4.w >> BK_BITS], 1); ebuf[sl] = make_int2(s4.w, d4.w);
    } else {
        for (long long k = e; k < E && k < e + 4; ++k) {
            const int d = dst[k];
            const int sl = atomicAdd(&bptr[d >> BK_BITS], 1);
            ebuf[sl] = make_int2(src[k], d);
        }
    }
}

// ---- csrfill: one block per bucket; locality-friendly CSR fill ------------
// After this: pos[n] = local end (global start = bsum[n>>10] + pos[n] - deg)
__global__ __launch_bounds__(256) void csrfill_kernel(
    const int2* __restrict__ ebuf, const int* __restrict__ bptr,
    const int* __restrict__ bsum, int* __restrict__ pos,
    int* __restrict__ esrc)
{
    const int b = blockIdx.x;
    const int first = b << BK_BITS;
    const int start = bsum[first >> 10] + pos[first];  // read BEFORE pos mutation
    const int end   = bptr[b];                          // final append ptr
    __syncthreads();
    for (int i = start + threadIdx.x; i < end; i += 256) {
        const int2 e = ebuf[i];
        const int slot = atomicAdd(&pos[e.y], 1);
        esrc[slot + bsum[e.y >> 10]] = e.x;
    }
}

// ---- direct fill (fallback when ws can't hold ebuf) -----------------------
__global__ __launch_bounds__(256) void fill_direct_kernel(
    const int* __restrict__ src, const int* __restrict__ dst,
    int* __restrict__ pos, const int* __restrict__ bsum,
    int* __restrict__ esrc, int E)
{
    const long long e = ((long long)blockIdx.x * 256 + threadIdx.x) * 4;
    if (e + 4 <= E) {
        const int4 s4 = *(const int4*)&src[e];
        const int4 d4 = *(const int4*)&dst[e];
        int sl;
        sl = atomicAdd(&pos[d4.x], 1); esrc[sl + bsum[d4.x >> 10]] = s4.x;
        sl = atomicAdd(&pos[d4.y], 1); esrc[sl + bsum[d4.y >> 10]] = s4.y;
        sl = atomicAdd(&pos[d4.z], 1); esrc[sl + bsum[d4.z >> 10]] = s4.z;
        sl = atomicAdd(&pos[d4.w], 1); esrc[sl + bsum[d4.w >> 10]] = s4.w;
    } else {
        for (long long k = e; k < E && k < e + 4; ++k) {
            const int d = dst[k];
            const int sl = atomicAdd(&pos[d], 1);
            esrc[sl + bsum[d >> 10]] = src[k];
        }
    }
}

// ===========================================================================
// Fused aggregate + ReLU(agg @ W^T + b).  bf16-gather variant.
//   NOTE: #pragma unroll 1 on the d4 loop is load-bearing — full unroll
//   blows past 256 VGPRs and spills ~3.5 GB to scratch (rounds 2-3).
// ===========================================================================
__global__ __launch_bounds__(256) void fused_kernel_bf(
    const float* __restrict__ h, const uint16* __restrict__ hb,
    const int* __restrict__ cnt, const int* __restrict__ pos,
    const int* __restrict__ bsum, const int* __restrict__ esrc,
    const float* __restrict__ Wt, const float* __restrict__ bias,
    float* __restrict__ out, int N)
{
    __shared__ float row_lds[NPB][DIM];   // 16 KB

    const int lane = threadIdx.x & 63;
    const int w    = threadIdx.x >> 6;
    const int nbase = blockIdx.x * NPB + w * 8;
    const int col2 = lane * 2;

#pragma unroll 1
    for (int i = 0; i < 8; ++i) {
        const int node = nbase + i;            // wave-uniform
        if (node >= N) break;
        const int deg = cnt[node];
        float ax, ay;
        if (deg == 0) {
            const float2 v = *(const float2*)&h[(size_t)node * DIM + col2];
            ax = v.x; ay = v.y;
        } else {
            const int start = pos[node] - deg + bsum[node >> 10];
            ax = 0.f; ay = 0.f;
#pragma unroll 4
            for (int k = 0; k < deg; ++k) {
                const int s = esrc[start + k];
                const uint32 u = *(const uint32*)&hb[(size_t)s * DIM + col2];
                ax += __uint_as_float(u << 16);
                ay += __uint_as_float(u & 0xffff0000u);
            }
            const float inv = 1.0f / (float)deg;
            ax *= inv; ay *= inv;
        }
        *(float2*)&row_lds[w * 8 + i][col2] = make_float2(ax, ay);
    }
    __syncthreads();

    const float2 bb = *(const float2*)&bias[col2];
    float acc0[8], acc1[8];
#pragma unroll
    for (int n = 0; n < 8; ++n) { acc0[n] = bb.x; acc1[n] = bb.y; }

#pragma unroll 1
    for (int d4 = 0; d4 < DIM; d4 += 4) {
        float4 a[8];
#pragma unroll
        for (int n = 0; n < 8; ++n)
            a[n] = *(const float4*)&row_lds[w * 8 + n][d4];   // broadcast
#pragma unroll
        for (int dd = 0; dd < 4; ++dd) {
            const float2 wt = *(const float2*)&Wt[(d4 + dd) * DIM + col2];
#pragma unroll
            for (int n = 0; n < 8; ++n) {
                const float av = dd == 0 ? a[n].x : dd == 1 ? a[n].y
                               : dd == 2 ? a[n].z : a[n].w;
                acc0[n] = fmaf(av, wt.x, acc0[n]);
                acc1[n] = fmaf(av, wt.y, acc1[n]);
            }
        }
    }

#pragma unroll
    for (int n = 0; n < 8; ++n) {
        const int node = nbase + n;
        if (node < N) {
            *(float2*)&out[(size_t)node * DIM + col2] =
                make_float2(fmaxf(acc0[n], 0.0f), fmaxf(acc1[n], 0.0f));
        }
    }
}

// ---- f32-gather fallback (if ws can't hold hb) ----------------------------
__global__ __launch_bounds__(256) void fused_kernel_f32(
    const float* __restrict__ h,
    const int* __restrict__ cnt, const int* __restrict__ pos,
    const int* __restrict__ bsum, const int* __restrict__ esrc,
    const float* __restrict__ Wt, const float* __restrict__ bias,
    float* __restrict__ out, int N)
{
    __shared__ float row_lds[NPB][DIM];
    const int lane = threadIdx.x & 63;
    const int w    = threadIdx.x >> 6;
    const int nbase = blockIdx.x * NPB + w * 8;
    const int col2 = lane * 2;

#pragma unroll 1
    for (int i = 0; i < 8; ++i) {
        const int node = nbase + i;
        if (node >= N) break;
        const int deg = cnt[node];
        float ax, ay;
        if (deg == 0) {
            const float2 v = *(const float2*)&h[(size_t)node * DIM + col2];
            ax = v.x; ay = v.y;
        } else {
            const int start = pos[node] - deg + bsum[node >> 10];
            ax = 0.f; ay = 0.f;
#pragma unroll 4
            for (int k = 0; k < deg; ++k) {
                const int s = esrc[start + k];
                const float2 v = *(const float2*)&h[(size_t)s * DIM + col2];
                ax += v.x; ay += v.y;
            }
            const float inv = 1.0f / (float)deg;
            ax *= inv; ay *= inv;
        }
        *(float2*)&row_lds[w * 8 + i][col2] = make_float2(ax, ay);
    }
    __syncthreads();

    const float2 bb = *(const float2*)&bias[col2];
    float acc0[8], acc1[8];
#pragma unroll
    for (int n = 0; n < 8; ++n) { acc0[n] = bb.x; acc1[n] = bb.y; }

#pragma unroll 1
    for (int d4 = 0; d4 < DIM; d4 += 4) {
        float4 a[8];
#pragma unroll
        for (int n = 0; n < 8; ++n)
            a[n] = *(const float4*)&row_lds[w * 8 + n][d4];
#pragma unroll
        for (int dd = 0; dd < 4; ++dd) {
            const float2 wt = *(const float2*)&Wt[(d4 + dd) * DIM + col2];
#pragma unroll
            for (int n = 0; n < 8; ++n) {
                const float av = dd == 0 ? a[n].x : dd == 1 ? a[n].y
                               : dd == 2 ? a[n].z : a[n].w;
                acc0[n] = fmaf(av, wt.x, acc0[n]);
                acc1[n] = fmaf(av, wt.y, acc1[n]);
            }
        }
    }

#pragma unroll
    for (int n = 0; n < 8; ++n) {
        const int node = nbase + n;
        if (node < N) {
            *(float2*)&out[(size_t)node * DIM + col2] =
                make_float2(fmaxf(acc0[n], 0.0f), fmaxf(acc1[n], 0.0f));
        }
    }
}

// ===========================================================================
extern "C" void kernel_launch(void* const* d_in, const int* in_sizes, int n_in,
                              void* d_out, int out_size, void* d_ws, size_t ws_size,
                              hipStream_t stream)
{
    const float* h  = (const float*)d_in[0];
    const int* src  = (const int*)d_in[1];
    const int* dst  = (const int*)d_in[2];
    const float* W  = (const float*)d_in[3];
    const float* b  = (const float*)d_in[4];
    float* out = (float*)d_out;

    const int N = in_sizes[0] / DIM;
    const int E = in_sizes[1];
    const long long ND = (long long)N * DIM;
    const int nb = (N + SCAN_CHUNK - 1) / SCAN_CHUNK;
    const int nbuck = (N + (1 << BK_BITS) - 1) >> BK_BITS;

    // Workspace layout
    const size_t off_cnt  = 0;
    const size_t off_pos  = (size_t)N * sizeof(int);
    const size_t off_esrc = off_pos + (size_t)N * sizeof(int);
    const size_t off_wt   = off_esrc + (size_t)E * sizeof(int);
    const size_t off_bsum = off_wt + (size_t)DIM * DIM * sizeof(float);
    const size_t off_bptr = off_bsum + 4096;
    const size_t off_hb   = (off_bptr + (size_t)nbuck * sizeof(int) + 255) & ~(size_t)255;
    const size_t off_ebuf = (off_hb + (size_t)ND * sizeof(uint16) + 255) & ~(size_t)255;
    const size_t req_bf   = off_ebuf;                                  // without ebuf
    const size_t req_full = off_ebuf + (size_t)E * sizeof(int2);       // with ebuf

    int*    cnt  = (int*)((char*)d_ws + off_cnt);
    int*    pos  = (int*)((char*)d_ws + off_pos);
    int*    esrc = (int*)((char*)d_ws + off_esrc);
    float*  Wt   = (float*)((char*)d_ws + off_wt);
    int*    bsum = (int*)((char*)d_ws + off_bsum);
    int*    bptr = (int*)((char*)d_ws + off_bptr);
    uint16* hb   = (uint16*)((char*)d_ws + off_hb);
    int2*   ebuf = (int2*)((char*)d_ws + off_ebuf);

    const int doConv   = (ws_size >= req_bf) ? 1 : 0;
    const int doBucket = (ws_size >= req_full) ? 1 : 0;
    const int nConv  = (int)((ND / 8 + 255) / 256);
    const int nEdgeB = (int)(((long long)E / 4 + 255) / 256) + 1;
    const int nPrep  = 64 + (doConv ? nConv : 0) + nEdgeB;

    hipMemsetAsync(cnt, 0, (size_t)N * sizeof(int), stream);
    prep_kernel<<<nPrep, 256, 0, stream>>>(W, Wt, h, hb, dst, cnt, E, ND, nConv, doConv);
    scanA_kernel<<<nb, 256, 0, stream>>>(cnt, pos, bsum, N);
    scanB_kernel<<<1, 1024, 0, stream>>>(bsum, nb, pos, bptr, nbuck);
    if (doBucket) {
        scatter_kernel<<<nEdgeB, 256, 0, stream>>>(src, dst, bptr, ebuf, E);
        csrfill_kernel<<<nbuck, 256, 0, stream>>>(ebuf, bptr, bsum, pos, esrc);
    } else {
        fill_direct_kernel<<<nEdgeB, 256, 0, stream>>>(src, dst, pos, bsum, esrc, E);
    }
    if (doConv)
        fused_kernel_bf<<<(N + NPB - 1) / NPB, 256, 0, stream>>>(h, hb, cnt, pos, bsum, esrc, Wt, b, out, N);
    else
        fused_kernel_f32<<<(N + NPB - 1) / NPB, 256, 0, stream>>>(h, cnt, pos, bsum, esrc, Wt, b, out, N);
}

// Round 8
// 268.950 us; speedup vs baseline: 1.8713x; 1.8713x over previous
//
#include <hip/hip_runtime.h>

#define DIM 128
#define NPB 32          // nodes per block in fused (4 waves x 8 nodes)
#define SCAN_CHUNK 1024 // nodes per scanA block
#define BK2_BITS 9      // 512 nodes per partition bucket
#define PART_T 32       // edges per thread in partition
#define PART_EB (256 * PART_T)  // 8192 edges per partition block

typedef unsigned int   uint32;
typedef unsigned short uint16;

__device__ __forceinline__ uint16 f32_to_bf16_rne(float f) {
    uint32 u = __float_as_uint(f);
    u += 0x7fffu + ((u >> 16) & 1u);
    return (uint16)(u >> 16);
}

// ===========================================================================
// prep: [0,64) transpose W ; [64,64+nConv) h->bf16 ; rest: per-node histogram
// ===========================================================================
__global__ __launch_bounds__(256) void prep_kernel(
    const float* __restrict__ W, float* __restrict__ Wt,
    const float* __restrict__ h, uint16* __restrict__ hb,
    const int* __restrict__ dst, int* __restrict__ cnt,
    int E, long long ND, int nConv, int doConv)
{
    const int bid = blockIdx.x;
    const int tid = threadIdx.x;
    if (bid < 64) {
        const int i = bid * 256 + tid;
        const int j = i >> 7, d = i & 127;
        Wt[d * DIM + j] = W[i];
    } else if (doConv && bid < 64 + nConv) {
        const long long base = ((long long)(bid - 64) * 256 + tid) * 8;
        if (base + 8 <= ND) {
            const float4 a = *(const float4*)&h[base];
            const float4 c = *(const float4*)&h[base + 4];
            uint4 v;
            v.x = (uint32)f32_to_bf16_rne(a.x) | ((uint32)f32_to_bf16_rne(a.y) << 16);
            v.y = (uint32)f32_to_bf16_rne(a.z) | ((uint32)f32_to_bf16_rne(a.w) << 16);
            v.z = (uint32)f32_to_bf16_rne(c.x) | ((uint32)f32_to_bf16_rne(c.y) << 16);
            v.w = (uint32)f32_to_bf16_rne(c.z) | ((uint32)f32_to_bf16_rne(c.w) << 16);
            *(uint4*)&hb[base] = v;
        }
    } else {
        const int hbase = 64 + (doConv ? nConv : 0);
        const long long e = ((long long)(bid - hbase) * 256 + tid) * 4;
        if (e + 4 <= E) {
            const int4 d4 = *(const int4*)&dst[e];
            atomicAdd(&cnt[d4.x], 1);
            atomicAdd(&cnt[d4.y], 1);
            atomicAdd(&cnt[d4.z], 1);
            atomicAdd(&cnt[d4.w], 1);
        } else {
            for (long long k = e; k < E && k < e + 4; ++k) atomicAdd(&cnt[dst[k]], 1);
        }
    }
}

// ---- scanA: per-chunk local exclusive scan + chunk totals -----------------
__global__ __launch_bounds__(256) void scanA_kernel(const int* __restrict__ cnt,
                                                    int* __restrict__ pos,
                                                    int* __restrict__ bsum, int N)
{
    __shared__ int ts[256];
    const int t = threadIdx.x;
    const int base = blockIdx.x * SCAN_CHUNK + t * 4;
    int v[4];
    int s = 0;
#pragma unroll
    for (int k = 0; k < 4; ++k) {
        v[k] = (base + k < N) ? cnt[base + k] : 0;
        s += v[k];
    }
    ts[t] = s;
    __syncthreads();
    for (int off = 1; off < 256; off <<= 1) {
        int x = (t >= off) ? ts[t - off] : 0;
        __syncthreads();
        ts[t] += x;
        __syncthreads();
    }
    int run = (t == 0) ? 0 : ts[t - 1];
    if (t == 255) bsum[blockIdx.x] = ts[255];
#pragma unroll
    for (int k = 0; k < 4; ++k) {
        if (base + k < N) pos[base + k] = run;   // LOCAL exclusive start
        run += v[k];
    }
}

// ---- scanB: excl-scan chunk totals + init bucket base/append pointers -----
__global__ __launch_bounds__(1024) void scanB_kernel(int* __restrict__ bsum, int nb,
                                                     const int* __restrict__ pos,
                                                     int* __restrict__ gptr,
                                                     int* __restrict__ bstart, int nbuck)
{
    __shared__ int ts[1024];
    const int t = threadIdx.x;
    ts[t] = (t < nb) ? bsum[t] : 0;
    __syncthreads();
    for (int off = 1; off < 1024; off <<= 1) {
        int x = (t >= off) ? ts[t - off] : 0;
        __syncthreads();
        ts[t] += x;
        __syncthreads();
    }
    if (t < nb) bsum[t] = (t == 0) ? 0 : ts[t - 1];   // chunk global offsets
    // bucket bk (512 nodes): global start = excl_chunk + pos[bk<<9]
    for (int bk = t; bk < nbuck; bk += 1024) {
        const int chunk = bk >> 1;                    // (bk<<9)>>10
        const int ec = (chunk == 0) ? 0 : ts[chunk - 1];
        const int st = ec + pos[bk << BK2_BITS];
        gptr[bk]   = st;   // mutable append pointer (pass 1)
        bstart[bk] = st;   // immutable copy (pass 2)
    }
}

// ---- partition: LDS-staged radix partition of edges into dst-buckets ------
// Each block: histogram 8192 edges in LDS -> one global atomicAdd per bucket
// (reserves a contiguous run) -> write edges to ebuf in block-private,
// mostly-coalesced runs. No cross-CU false sharing (round-7 post-mortem).
__global__ __launch_bounds__(256) void partition_kernel(
    const int* __restrict__ src, const int* __restrict__ dst,
    int* __restrict__ gptr, int2* __restrict__ ebuf, int E, int nbuck)
{
    __shared__ int hist[256];     // nbuck <= 256
    const int t = threadIdx.x;
    const long long e0 = (long long)blockIdx.x * PART_EB;

    for (int i = t; i < 256; i += 256) hist[i] = 0;
    __syncthreads();

    // ---- step 1: count ----
#pragma unroll 1
    for (int j = 0; j < PART_T / 4; ++j) {
        const long long be = e0 + ((long long)(j * 256 + t)) * 4;
        if (be + 4 <= E) {
            const int4 d4 = *(const int4*)&dst[be];
            atomicAdd(&hist[d4.x >> BK2_BITS], 1);
            atomicAdd(&hist[d4.y >> BK2_BITS], 1);
            atomicAdd(&hist[d4.z >> BK2_BITS], 1);
            atomicAdd(&hist[d4.w >> BK2_BITS], 1);
        } else {
            for (long long k = be; k < E && k < be + 4; ++k)
                atomicAdd(&hist[dst[k] >> BK2_BITS], 1);
        }
    }
    __syncthreads();

    // ---- step 2: reserve global runs (1 atomic per touched bucket) ----
    for (int i = t; i < nbuck; i += 256) {
        const int c = hist[i];
        hist[i] = (c > 0) ? atomicAdd(&gptr[i], c) : 0;
    }
    __syncthreads();

    // ---- step 3: scatter into reserved runs (block-private, coalesced) ----
#pragma unroll 1
    for (int j = 0; j < PART_T / 4; ++j) {
        const long long be = e0 + ((long long)(j * 256 + t)) * 4;
        if (be + 4 <= E) {
            const int4 s4 = *(const int4*)&src[be];
            const int4 d4 = *(const int4*)&dst[be];
            int sl;
            sl = atomicAdd(&hist[d4.x >> BK2_BITS], 1); ebuf[sl] = make_int2(s4.x, d4.x);
            sl = atomicAdd(&hist[d4.y >> BK2_BITS], 1); ebuf[sl] = make_int2(s4.y, d4.y);
            sl = atomicAdd(&hist[d4.z >> BK2_BITS], 1); ebuf[sl] = make_int2(s4.z, d4.z);
            sl = atomicAdd(&hist[d4.w >> BK2_BITS], 1); ebuf[sl] = make_int2(s4.w, d4.w);
        } else {
            for (long long k = be; k < E && k < be + 4; ++k) {
                const int d = dst[k];
                const int sl = atomicAdd(&hist[d >> BK2_BITS], 1);
                ebuf[sl] = make_int2(src[k], d);
            }
        }
    }
}

// ---- csrfill: one block per bucket; pos/esrc windows are L2-resident ------
// After this: pos[n] = local end (global start = bsum[n>>10] + pos[n] - deg)
__global__ __launch_bounds__(256) void csrfill_kernel(
    const int2* __restrict__ ebuf, const int* __restrict__ bstart,
    const int* __restrict__ gptr, const int* __restrict__ bsum,
    int* __restrict__ pos, int* __restrict__ esrc)
{
    const int b = blockIdx.x;
    const int start = bstart[b];
    const int end   = gptr[b];        // final append pointer after pass 1
    for (int i = start + threadIdx.x; i < end; i += 256) {
        const int2 e = ebuf[i];
        const int slot = atomicAdd(&pos[e.y], 1);
        esrc[slot + bsum[e.y >> 10]] = e.x;
    }
}

// ---- direct fill (fallback when ws can't hold ebuf) -----------------------
__global__ __launch_bounds__(256) void fill_direct_kernel(
    const int* __restrict__ src, const int* __restrict__ dst,
    int* __restrict__ pos, const int* __restrict__ bsum,
    int* __restrict__ esrc, int E)
{
    const long long e = ((long long)blockIdx.x * 256 + threadIdx.x) * 4;
    if (e + 4 <= E) {
        const int4 s4 = *(const int4*)&src[e];
        const int4 d4 = *(const int4*)&dst[e];
        int sl;
        sl = atomicAdd(&pos[d4.x], 1); esrc[sl + bsum[d4.x >> 10]] = s4.x;
        sl = atomicAdd(&pos[d4.y], 1); esrc[sl + bsum[d4.y >> 10]] = s4.y;
        sl = atomicAdd(&pos[d4.z], 1); esrc[sl + bsum[d4.z >> 10]] = s4.z;
        sl = atomicAdd(&pos[d4.w], 1); esrc[sl + bsum[d4.w >> 10]] = s4.w;
    } else {
        for (long long k = e; k < E && k < e + 4; ++k) {
            const int d = dst[k];
            const int sl = atomicAdd(&pos[d], 1);
            esrc[sl + bsum[d >> 10]] = src[k];
        }
    }
}

// ===========================================================================
// Fused aggregate + ReLU(agg @ W^T + b).  bf16-gather variant.
//   NOTE: #pragma unroll 1 on the d4 loop is load-bearing — full unroll
//   blows past 256 VGPRs and spills ~3.5 GB to scratch (rounds 2-3).
// ===========================================================================
__global__ __launch_bounds__(256) void fused_kernel_bf(
    const float* __restrict__ h, const uint16* __restrict__ hb,
    const int* __restrict__ cnt, const int* __restrict__ pos,
    const int* __restrict__ bsum, const int* __restrict__ esrc,
    const float* __restrict__ Wt, const float* __restrict__ bias,
    float* __restrict__ out, int N)
{
    __shared__ float row_lds[NPB][DIM];   // 16 KB

    const int lane = threadIdx.x & 63;
    const int w    = threadIdx.x >> 6;
    const int nbase = blockIdx.x * NPB + w * 8;
    const int col2 = lane * 2;

#pragma unroll 1
    for (int i = 0; i < 8; ++i) {
        const int node = nbase + i;            // wave-uniform
        if (node >= N) break;
        const int deg = cnt[node];
        float ax, ay;
        if (deg == 0) {
            const float2 v = *(const float2*)&h[(size_t)node * DIM + col2];
            ax = v.x; ay = v.y;
        } else {
            const int start = pos[node] - deg + bsum[node >> 10];
            ax = 0.f; ay = 0.f;
#pragma unroll 4
            for (int k = 0; k < deg; ++k) {
                const int s = esrc[start + k];
                const uint32 u = *(const uint32*)&hb[(size_t)s * DIM + col2];
                ax += __uint_as_float(u << 16);
                ay += __uint_as_float(u & 0xffff0000u);
            }
            const float inv = 1.0f / (float)deg;
            ax *= inv; ay *= inv;
        }
        *(float2*)&row_lds[w * 8 + i][col2] = make_float2(ax, ay);
    }
    __syncthreads();

    const float2 bb = *(const float2*)&bias[col2];
    float acc0[8], acc1[8];
#pragma unroll
    for (int n = 0; n < 8; ++n) { acc0[n] = bb.x; acc1[n] = bb.y; }

#pragma unroll 1
    for (int d4 = 0; d4 < DIM; d4 += 4) {
        float4 a[8];
#pragma unroll
        for (int n = 0; n < 8; ++n)
            a[n] = *(const float4*)&row_lds[w * 8 + n][d4];   // broadcast
#pragma unroll
        for (int dd = 0; dd < 4; ++dd) {
            const float2 wt = *(const float2*)&Wt[(d4 + dd) * DIM + col2];
#pragma unroll
            for (int n = 0; n < 8; ++n) {
                const float av = dd == 0 ? a[n].x : dd == 1 ? a[n].y
                               : dd == 2 ? a[n].z : a[n].w;
                acc0[n] = fmaf(av, wt.x, acc0[n]);
                acc1[n] = fmaf(av, wt.y, acc1[n]);
            }
        }
    }

#pragma unroll
    for (int n = 0; n < 8; ++n) {
        const int node = nbase + n;
        if (node < N) {
            *(float2*)&out[(size_t)node * DIM + col2] =
                make_float2(fmaxf(acc0[n], 0.0f), fmaxf(acc1[n], 0.0f));
        }
    }
}

// ---- f32-gather fallback (if ws can't hold hb) ----------------------------
__global__ __launch_bounds__(256) void fused_kernel_f32(
    const float* __restrict__ h,
    const int* __restrict__ cnt, const int* __restrict__ pos,
    const int* __restrict__ bsum, const int* __restrict__ esrc,
    const float* __restrict__ Wt, const float* __restrict__ bias,
    float* __restrict__ out, int N)
{
    __shared__ float row_lds[NPB][DIM];
    const int lane = threadIdx.x & 63;
    const int w    = threadIdx.x >> 6;
    const int nbase = blockIdx.x * NPB + w * 8;
    const int col2 = lane * 2;

#pragma unroll 1
    for (int i = 0; i < 8; ++i) {
        const int node = nbase + i;
        if (node >= N) break;
        const int deg = cnt[node];
        float ax, ay;
        if (deg == 0) {
            const float2 v = *(const float2*)&h[(size_t)node * DIM + col2];
            ax = v.x; ay = v.y;
        } else {
            const int start = pos[node] - deg + bsum[node >> 10];
            ax = 0.f; ay = 0.f;
#pragma unroll 4
            for (int k = 0; k < deg; ++k) {
                const int s = esrc[start + k];
                const float2 v = *(const float2*)&h[(size_t)s * DIM + col2];
                ax += v.x; ay += v.y;
            }
            const float inv = 1.0f / (float)deg;
            ax *= inv; ay *= inv;
        }
        *(float2*)&row_lds[w * 8 + i][col2] = make_float2(ax, ay);
    }
    __syncthreads();

    const float2 bb = *(const float2*)&bias[col2];
    float acc0[8], acc1[8];
#pragma unroll
    for (int n = 0; n < 8; ++n) { acc0[n] = bb.x; acc1[n] = bb.y; }

#pragma unroll 1
    for (int d4 = 0; d4 < DIM; d4 += 4) {
        float4 a[8];
#pragma unroll
        for (int n = 0; n < 8; ++n)
            a[n] = *(const float4*)&row_lds[w * 8 + n][d4];
#pragma unroll
        for (int dd = 0; dd < 4; ++dd) {
            const float2 wt = *(const float2*)&Wt[(d4 + dd) * DIM + col2];
#pragma unroll
            for (int n = 0; n < 8; ++n) {
                const float av = dd == 0 ? a[n].x : dd == 1 ? a[n].y
                               : dd == 2 ? a[n].z : a[n].w;
                acc0[n] = fmaf(av, wt.x, acc0[n]);
                acc1[n] = fmaf(av, wt.y, acc1[n]);
            }
        }
    }

#pragma unroll
    for (int n = 0; n < 8; ++n) {
        const int node = nbase + n;
        if (node < N) {
            *(float2*)&out[(size_t)node * DIM + col2] =
                make_float2(fmaxf(acc0[n], 0.0f), fmaxf(acc1[n], 0.0f));
        }
    }
}

// ===========================================================================
extern "C" void kernel_launch(void* const* d_in, const int* in_sizes, int n_in,
                              void* d_out, int out_size, void* d_ws, size_t ws_size,
                              hipStream_t stream)
{
    const float* h  = (const float*)d_in[0];
    const int* src  = (const int*)d_in[1];
    const int* dst  = (const int*)d_in[2];
    const float* W  = (const float*)d_in[3];
    const float* b  = (const float*)d_in[4];
    float* out = (float*)d_out;

    const int N = in_sizes[0] / DIM;
    const int E = in_sizes[1];
    const long long ND = (long long)N * DIM;
    const int nb = (N + SCAN_CHUNK - 1) / SCAN_CHUNK;
    const int nbuck = (N + (1 << BK2_BITS) - 1) >> BK2_BITS;

    // Workspace layout
    const size_t off_cnt  = 0;
    const size_t off_pos  = (size_t)N * sizeof(int);
    const size_t off_esrc = off_pos + (size_t)N * sizeof(int);
    const size_t off_wt   = off_esrc + (size_t)E * sizeof(int);
    const size_t off_bsum = off_wt + (size_t)DIM * DIM * sizeof(float);
    const size_t off_gp   = off_bsum + 4096;
    const size_t off_bs2  = off_gp + 1024;
    const size_t off_hb   = (off_bs2 + 1024 + 255) & ~(size_t)255;
    const size_t off_ebuf = (off_hb + (size_t)ND * sizeof(uint16) + 255) & ~(size_t)255;
    const size_t req_bf   = off_ebuf;                                  // without ebuf
    const size_t req_full = off_ebuf + (size_t)E * sizeof(int2);       // with ebuf

    int*    cnt    = (int*)((char*)d_ws + off_cnt);
    int*    pos    = (int*)((char*)d_ws + off_pos);
    int*    esrc   = (int*)((char*)d_ws + off_esrc);
    float*  Wt     = (float*)((char*)d_ws + off_wt);
    int*    bsum   = (int*)((char*)d_ws + off_bsum);
    int*    gptr   = (int*)((char*)d_ws + off_gp);
    int*    bstart = (int*)((char*)d_ws + off_bs2);
    uint16* hb     = (uint16*)((char*)d_ws + off_hb);
    int2*   ebuf   = (int2*)((char*)d_ws + off_ebuf);

    const int doConv   = (ws_size >= req_bf) ? 1 : 0;
    const int doBucket = (ws_size >= req_full && nbuck <= 256) ? 1 : 0;
    const int nConv  = (int)((ND / 8 + 255) / 256);
    const int nEdgeB = (int)(((long long)E / 4 + 255) / 256) + 1;
    const int nPrep  = 64 + (doConv ? nConv : 0) + nEdgeB;
    const int nPart  = (int)(((long long)E + PART_EB - 1) / PART_EB);

    hipMemsetAsync(cnt, 0, (size_t)N * sizeof(int), stream);
    prep_kernel<<<nPrep, 256, 0, stream>>>(W, Wt, h, hb, dst, cnt, E, ND, nConv, doConv);
    scanA_kernel<<<nb, 256, 0, stream>>>(cnt, pos, bsum, N);
    scanB_kernel<<<1, 1024, 0, stream>>>(bsum, nb, pos, gptr, bstart, nbuck);
    if (doBucket) {
        partition_kernel<<<nPart, 256, 0, stream>>>(src, dst, gptr, ebuf, E, nbuck);
        csrfill_kernel<<<nbuck, 256, 0, stream>>>(ebuf, bstart, gptr, bsum, pos, esrc);
    } else {
        fill_direct_kernel<<<nEdgeB, 256, 0, stream>>>(src, dst, pos, bsum, esrc, E);
    }
    if (doConv)
        fused_kernel_bf<<<(N + NPB - 1) / NPB, 256, 0, stream>>>(h, hb, cnt, pos, bsum, esrc, Wt, b, out, N);
    else
        fused_kernel_f32<<<(N + NPB - 1) / NPB, 256, 0, stream>>>(h, cnt, pos, bsum, esrc, Wt, b, out, N);
}